// Round 9
// baseline (102.287 us; speedup 1.0000x reference)
//
#include <hip/hip_runtime.h>

// Problem constants (from reference): M=8 samples, N=4096, K=16 filters.
#define NN 4096
#define MM 8
#define KK 16

// Native clang vector type (HIP float4 struct is rejected by
// __builtin_nontemporal_load; ext vectors get componentwise ops).
typedef float v4f __attribute__((ext_vector_type(4)));

// ws layout (all write-before-read every call; no memset needed):
//   col     @ 0                : 4096 floats (16 KB)
//   partial @ 4096             : 64 x 4096 floats (1 MB), partial[rg][m]
//   Wt      @ 4096 + 64*4096   : 4096 x 16 floats (256 KB), Wt[i][k]
#define WS_COL     0
#define WS_PARTIAL 4096
#define WS_WT      (4096 + 64 * 4096)

// Stage 1: grid (16, 65).
//  y<64 : partial[y][m] = sum of 64 rows of L (row-group y), column stripe x.
//         NT float4 loads, 4 row-subgroups reduced via LDS tree, no atomics.
//  y==64: Wt[i][k] = W[k][i] transpose (independent of L; runs in stage1's
//         shadow instead of serializing in stage2).
__global__ void __launch_bounds__(256) colsum_stage1(const float* __restrict__ L,
                                                     const float* __restrict__ W,
                                                     float* __restrict__ ws) {
    const int t = threadIdx.x;
    if (blockIdx.y == 64) {
        float* __restrict__ Wt = ws + WS_WT;
        for (int o = blockIdx.x * 256 + t; o < NN * KK; o += 16 * 256) {
            const int i = o >> 4;                    // simplex index
            const int k = o & 15;                    // filter index
            Wt[o] = W[k * NN + i];
        }
        return;
    }
    const int m4 = blockIdx.x * 64 + (t & 63);        // float4 column slot 0..1023
    const int r0 = blockIdx.y * 64 + (t >> 6) * 16;   // this thread's 16 rows
    const v4f* __restrict__ L4 = reinterpret_cast<const v4f*>(L);
    v4f acc = {0.f, 0.f, 0.f, 0.f};
#pragma unroll
    for (int j = 0; j < 16; ++j) {
        acc += __builtin_nontemporal_load(&L4[(size_t)(r0 + j) * (NN / 4) + m4]);
    }
    __shared__ v4f red[256];
    red[t] = acc;
    __syncthreads();
    if (t < 64) {
        const v4f s = red[t] + red[t + 64] + red[t + 128] + red[t + 192];
        reinterpret_cast<v4f*>(ws + WS_PARTIAL)[blockIdx.y * (NN / 4) + blockIdx.x * 64 + t] = s;
    }
}

// Stage 2: 4 blocks — col[m] = sum_rg partial[rg][m] (1 MB, cache-resident).
__global__ void __launch_bounds__(256) colsum_stage2(float* __restrict__ ws) {
    const int slot = blockIdx.x * 256 + threadIdx.x;   // float4 column slot
    const v4f* __restrict__ p4 = reinterpret_cast<const v4f*>(ws + WS_PARTIAL);
    v4f acc = {0.f, 0.f, 0.f, 0.f};
#pragma unroll 8
    for (int j = 0; j < 64; ++j) {
        acc += p4[j * (NN / 4) + slot];
    }
    reinterpret_cast<v4f*>(ws + WS_COL)[slot] = acc;
}

// Fast overflow-safe tanh: copysign(1 - 2/(e^{2|a|}+1), a).
// |a| large -> e = inf -> result ±1 (no NaN). ~1e-6 abs error, threshold 0.28.
__device__ __forceinline__ float fast_tanh(float a) {
    const float e = __expf(2.f * fabsf(a));
    const float t = 1.f - 2.f * __builtin_amdgcn_rcpf(e + 1.f);
    return copysignf(t, a);
}

// Stage 3 (conv): per output row (b,i):
//   s = dot(x[b,i,:], col);  out[b,i] = sum_k tanh(Wt[i][k] * s)
// One 64-lane wave per row (proven stream pattern). col staged in LDS:
// col reads leave the VMEM path (lgkmcnt, not vmcnt) so every VMEM queue
// slot holds an x prefetch, and col can never be evicted. x is NT.
__global__ void __launch_bounds__(256) conv_kernel(const float* __restrict__ x,
                                                   const float* __restrict__ ws,
                                                   float* __restrict__ out) {
    __shared__ v4f col_lds[NN / 4];                 // 16 KB -> 8 blocks/CU max
    const int t = threadIdx.x;
#pragma unroll
    for (int j = 0; j < 4; ++j) {
        col_lds[j * 256 + t] = reinterpret_cast<const v4f*>(ws + WS_COL)[j * 256 + t];
    }
    __syncthreads();

    const int wave = t >> 6;                   // 0..3
    const int lane = t & 63;
    const int row  = blockIdx.x * 4 + wave;    // 0 .. 32767  (= b*NN + i)
    const int i    = row & (NN - 1);

    const v4f* __restrict__ xr = reinterpret_cast<const v4f*>(x) + (size_t)row * (NN / 4);

    float acc = 0.f;
#pragma unroll 4
    for (int it = 0; it < NN / 4 / 64; ++it) {      // 16 iterations
        const v4f a = __builtin_nontemporal_load(&xr[it * 64 + lane]);
        const v4f c = col_lds[it * 64 + lane];
        const v4f p = a * c;
        acc += p.x + p.y + p.z + p.w;
    }

    // Butterfly reduce: every lane ends with the full dot product s.
#pragma unroll
    for (int off = 32; off >= 1; off >>= 1)
        acc += __shfl_xor(acc, off, 64);

    // Lanes 0..15 each evaluate one filter (coalesced 64B Wt line).
    float r = 0.f;
    if (lane < KK) r = fast_tanh((ws + WS_WT)[i * KK + lane] * acc);
#pragma unroll
    for (int off = 8; off >= 1; off >>= 1)
        r += __shfl_down(r, off, 64);

    if (lane == 0) out[row] = r;
}

extern "C" void kernel_launch(void* const* d_in, const int* in_sizes, int n_in,
                              void* d_out, int out_size, void* d_ws, size_t ws_size,
                              hipStream_t stream) {
    const float* x = (const float*)d_in[0];  // [M, N, N]
    const float* L = (const float*)d_in[1];  // [N, N]
    const float* W = (const float*)d_in[2];  // [K, N]
    float* out = (float*)d_out;              // [M, N] fp32
    float* ws  = (float*)d_ws;               // scratch (col | partial | Wt)

    colsum_stage1<<<dim3(16, 65), 256, 0, stream>>>(L, W, ws);
    colsum_stage2<<<4, 256, 0, stream>>>(ws);
    conv_kernel<<<(MM * NN) / 4, 256, 0, stream>>>(x, ws, out);
}